// Round 5
// baseline (151.226 us; speedup 1.0000x reference)
//
#include <hip/hip_runtime.h>
#include <math.h>

// B=8, N=2048, coords [B,N,3] f32. LDDT loss, upper-triangle formulation:
// both distance matrices are symmetric, so num/den over {j>i} equals the
// full-matrix ratio; j>i also excludes the diagonal (reference's
// true_d > 1e-8 test is vacuous for distinct points).
//
// V6: single main dispatch + tiny init dispatch. The dependent 1-block
// reduce kernel (launch gap + ~4us) is replaced by a last-block-done
// reduction inside the main kernel (device-scope atomicAdd arrival counter,
// threadfence release/acquire; does NOT depend on co-residency or dispatch
// order -> G16-safe). The counter lives in poisoned workspace, so a 1-wave
// init kernel zeroes it first (~1.5us, no dependency chain cost).
// Evidence trail: V4 (-25% LDS instrs, -8% pairs) was NEUTRAL -> inner loop
// off the critical path. V5 cooperative grid.sync cost ~60us -> dead.
// V2 (uniform-pointer loads) and V3 (v_readlane broadcast) both SLOWER than
// LDS same-address broadcast -- do not revisit.
constexpr int B  = 8;
constexpr int N  = 2048;
constexpr int TI = 256;        // i-points per block (== threads)
constexpr int TJ = 64;         // j-points per block (== one wave)
constexpr int TILES = 144;     // sum_{a=0..7} (32 - 4a): j-tiles with any j>i

template <bool CHECK>
__device__ __forceinline__ void do_pair(
    float jx, float jy, float jz, float ux, float uy, float uz,
    float pix, float piy, float piz, float tix, float tiy, float tiz,
    int jj,
    unsigned& c0, unsigned& c1, unsigned& c2, unsigned& c3, unsigned& cd)
{
    float dx = pix - jx, dy = piy - jy, dz = piz - jz;
    float pd2 = fmaf(dx, dx, fmaf(dy, dy, dz * dz));
    float ex = tix - ux, ey = tiy - uy, ez = tiz - uz;
    float td2 = fmaf(ex, ex, fmaf(ey, ey, ez * ez));

    // local mask (squared domain): true_d < 15
    unsigned long long m = __ballot(td2 < 225.0f);
    // diagonal tile: j>i <=> jj>lane <=> lane in [0,jj) -> constant mask
    if (CHECK) m &= (jj < 64) ? ((1ull << jj) - 1ull) : ~0ull;

    float diff = fabsf(__builtin_amdgcn_sqrtf(pd2) - __builtin_amdgcn_sqrtf(td2));

    // cumulative bins: score = .5*[d<.5] + .25*[d<1] + .125*[d<2] + .125*[d<4]
    c0 += __popcll(m & __ballot(diff < 0.5f));
    c1 += __popcll(m & __ballot(diff < 1.0f));
    c2 += __popcll(m & __ballot(diff < 2.0f));
    c3 += __popcll(m & __ballot(diff < 4.0f));
    cd += __popcll(m);
}

template <bool CHECK>
__device__ __forceinline__ void inner_loop(
    const float4* __restrict__ s4,   // packed j-tile: 3 float4 per 2 j-points
    float pix, float piy, float piz,
    float tix, float tiy, float tiz,
    unsigned& c0, unsigned& c1, unsigned& c2, unsigned& c3, unsigned& cd)
{
    #pragma unroll 4
    for (int q = 0; q < TJ / 2; ++q) {
        // same address across all 64 lanes -> LDS broadcast, conflict-free
        float4 A  = s4[3 * q + 0];  // {p0.x, p0.y, p0.z, t0.x}
        float4 Bq = s4[3 * q + 1];  // {t0.y, t0.z, p1.x, p1.y}
        float4 Cq = s4[3 * q + 2];  // {p1.z, t1.x, t1.y, t1.z}

        do_pair<CHECK>(A.x, A.y, A.z, A.w, Bq.x, Bq.y,
                       pix, piy, piz, tix, tiy, tiz, 2 * q,
                       c0, c1, c2, c3, cd);
        do_pair<CHECK>(Bq.z, Bq.w, Cq.x, Cq.y, Cq.z, Cq.w,
                       pix, piy, piz, tix, tiy, tiz, 2 * q + 1,
                       c0, c1, c2, c3, cd);
    }
}

// compute this block's (num, den) and store to its private slot
__device__ __forceinline__ void partial_body(
    const float* __restrict__ pred, const float* __restrict__ truec,
    float* __restrict__ part)
{
    const int b = blockIdx.y;
    // decode linear tile index -> (a = i-tile, k = j-subtile rel. index)
    int r = blockIdx.x, a = 0;
    while (r >= 32 - 4 * a) { r -= 32 - 4 * a; ++a; }
    const int k = r;                  // c = 4a + k, k in [0, 32-4a)
    const int i0 = a * TI;
    const int j0 = (4 * a + k) * TJ;
    const int t = threadIdx.x;
    const int w = t >> 6;
    const int lane = t & 63;

    // packed j-tile: sj[6*j .. 6*j+5] = {px,py,pz,tx,ty,tz} of point j0+j
    __shared__ float sj[TJ * 6];
    if (t < TJ) {
        const float* pp = pred  + ((size_t)b * N + j0 + t) * 3;
        const float* tp = truec + ((size_t)b * N + j0 + t) * 3;
        sj[6 * t + 0] = pp[0];
        sj[6 * t + 1] = pp[1];
        sj[6 * t + 2] = pp[2];
        sj[6 * t + 3] = tp[0];
        sj[6 * t + 4] = tp[1];
        sj[6 * t + 5] = tp[2];
    }
    __syncthreads();

    unsigned c0 = 0, c1 = 0, c2 = 0, c3 = 0, cd = 0;

    if (k >= w) {                     // k<w: whole wave is j<i -> zero
        const int i = i0 + t;
        const float* pi = pred  + ((size_t)b * N + i) * 3;
        const float* ti = truec + ((size_t)b * N + i) * 3;
        const float pix = pi[0], piy = pi[1], piz = pi[2];
        const float tix = ti[0], tiy = ti[1], tiz = ti[2];
        const float4* s4 = reinterpret_cast<const float4*>(sj);

        if (k > w) {                  // strictly above diagonal: no check
            inner_loop<false>(s4, pix, piy, piz, tix, tiy, tiz,
                              c0, c1, c2, c3, cd);
        } else {                      // k == w: diagonal 64x64 block
            inner_loop<true>(s4, pix, piy, piz, tix, tiy, tiz,
                             c0, c1, c2, c3, cd);
        }
    }

    // counters are wave-uniform (ballot-derived): lane 0 of each wave has them
    __shared__ float rnum[TI / 64];
    __shared__ float rden[TI / 64];
    if (lane == 0) {
        rnum[w] = 0.125f * (float)(4u * c0 + 2u * c1 + c2 + c3);
        rden[w] = (float)cd;
    }
    __syncthreads();

    if (t == 0) {
        float n = 0.0f, d = 0.0f;
        #pragma unroll
        for (int q = 0; q < TI / 64; ++q) { n += rnum[q]; d += rden[q]; }
        // plain store to this block's private slot -- NO atomics, no memset
        float* slot = part + ((size_t)b * TILES + blockIdx.x) * 2;
        slot[0] = n;
        slot[1] = d;
    }
}

// reduce part[B][TILES][2] -> out[0]; same summation order as the previous
// dedicated reduce kernel (stride-64 lane sums, shfl tree, batch order) so
// the result stays bit-identical. nwaves waves; wave w handles batches
// w, w+nwaves, ...
__device__ __forceinline__ void reduce_body(
    const float* __restrict__ part, float* __restrict__ out,
    int t, int nwaves)
{
    const int w = t >> 6;
    const int l = t & 63;

    __shared__ float acc[B];
    for (int bb = w; bb < B; bb += nwaves) {
        float n = 0.0f, d = 0.0f;
        for (int s = l; s < TILES; s += 64) {
            const float* slot = part + ((size_t)bb * TILES + s) * 2;
            n += slot[0];
            d += slot[1];
        }
        #pragma unroll
        for (int off = 32; off > 0; off >>= 1) {
            n += __shfl_down(n, off, 64);
            d += __shfl_down(d, off, 64);
        }
        if (l == 0) acc[bb] = 1.0f - n / fmaxf(d, 1e-8f);
    }
    __syncthreads();

    if (t == 0) {
        float s = 0.0f;
        #pragma unroll
        for (int b = 0; b < B; ++b) s += acc[b];
        out[0] = s / (float)B;
    }
}

// tiny init: zero the arrival counter (workspace is poisoned every iteration)
__global__ __launch_bounds__(64) void lddt_init(unsigned* __restrict__ ctr)
{
    if (threadIdx.x == 0) *ctr = 0u;
}

// main: partial + last-block-done reduce (no grid barrier, no 2nd dependent
// dispatch). Release: each block fences its slot store, then atomicAdd
// (device scope by default on CDNA). Acquire: the last block's RMW + fence,
// then it reads all 288 slots. Correct under any dispatch order.
__global__ __launch_bounds__(TI) void lddt_main(
    const float* __restrict__ pred, const float* __restrict__ truec,
    float* __restrict__ part, unsigned* __restrict__ ctr,
    float* __restrict__ out)
{
    partial_body(pred, truec, part);

    __shared__ unsigned last;
    __threadfence();                  // release this block's slot store
    if (threadIdx.x == 0) {
        unsigned old = atomicAdd(ctr, 1u);
        last = (old == (unsigned)(B * TILES - 1)) ? 1u : 0u;
    }
    __syncthreads();

    if (last) {
        __threadfence();              // acquire all blocks' slot stores
        reduce_body(part, out, threadIdx.x, TI / 64);
    }
}

extern "C" void kernel_launch(void* const* d_in, const int* in_sizes, int n_in,
                              void* d_out, int out_size, void* d_ws, size_t ws_size,
                              hipStream_t stream)
{
    const float* pred  = (const float*)d_in[0];
    const float* truec = (const float*)d_in[1];
    float* out  = (float*)d_out;
    float* part = (float*)d_ws;                           // 2304 floats = 9216 B
    unsigned* ctr = (unsigned*)((char*)d_ws + 9216);      // arrival counter

    dim3 grid(TILES, B);
    lddt_init<<<1, 64, 0, stream>>>(ctr);
    lddt_main<<<grid, TI, 0, stream>>>(pred, truec, part, ctr, out);
}

// Round 6
// 73.605 us; speedup vs baseline: 2.0546x; 2.0546x over previous
//
#include <hip/hip_runtime.h>
#include <math.h>

// B=8, N=2048, coords [B,N,3] f32. LDDT loss, upper-triangle formulation:
// both distance matrices are symmetric, so num/den over {j>i} equals the
// full-matrix ratio; j>i also excludes the diagonal (reference's
// true_d > 1e-8 test is vacuous for distinct points).
//
// V7 = proven V4 inner loop (packed j-tile LDS broadcast, ballot+popcount,
// wave-level triangle skip) with TI=512 (8 waves/block): block count
// 1152 -> 640, j-tile stagings and per-block barriers amortized 2x.
// Rationale: V6's counters showed the partial body's pipes are <50% busy
// (VALU-active ~9us vs ~20us wall) and V4's -25% LDS / -8% pairs was
// NEUTRAL -> the kernel is per-block-overhead/latency-bound, so shrink
// block count, not inner-loop work.
// Dead ends (measured): V2 uniform-pointer loads (+3), V3 v_readlane (+6),
// V5 cooperative grid.sync (+60 in-kernel), V6 last-block atomic+fence
// (+80: 1152 single-address device atomics across XCDs ~88ns each).
// Exactness: per-slot num is a multiple of 1/8 with 8*num <= 16,769,024 <
// 2^24 and den <= 2,096,128 < 2^24 -> all fp32 sums exact in ANY order,
// so the 80-slot reduce is bit-identical to the 144-slot one (absmax 0.0).
constexpr int B  = 8;
constexpr int N  = 2048;
constexpr int TI = 512;        // i-points per block (== threads, 8 waves)
constexpr int TJ = 64;         // j-points per block (== one wave)
constexpr int NA = N / TI;     // 4 i-tiles
constexpr int TILES = 80;      // sum_{a=0..3} (32 - 8a): j-tiles with any j>i

template <bool CHECK>
__device__ __forceinline__ void do_pair(
    float jx, float jy, float jz, float ux, float uy, float uz,
    float pix, float piy, float piz, float tix, float tiy, float tiz,
    int jj,
    unsigned& c0, unsigned& c1, unsigned& c2, unsigned& c3, unsigned& cd)
{
    float dx = pix - jx, dy = piy - jy, dz = piz - jz;
    float pd2 = fmaf(dx, dx, fmaf(dy, dy, dz * dz));
    float ex = tix - ux, ey = tiy - uy, ez = tiz - uz;
    float td2 = fmaf(ex, ex, fmaf(ey, ey, ez * ez));

    // local mask (squared domain): true_d < 15
    unsigned long long m = __ballot(td2 < 225.0f);
    // diagonal tile: j>i <=> jj>lane <=> lane in [0,jj) -> constant mask
    if (CHECK) m &= (jj < 64) ? ((1ull << jj) - 1ull) : ~0ull;

    float diff = fabsf(__builtin_amdgcn_sqrtf(pd2) - __builtin_amdgcn_sqrtf(td2));

    // cumulative bins: score = .5*[d<.5] + .25*[d<1] + .125*[d<2] + .125*[d<4]
    c0 += __popcll(m & __ballot(diff < 0.5f));
    c1 += __popcll(m & __ballot(diff < 1.0f));
    c2 += __popcll(m & __ballot(diff < 2.0f));
    c3 += __popcll(m & __ballot(diff < 4.0f));
    cd += __popcll(m);
}

template <bool CHECK>
__device__ __forceinline__ void inner_loop(
    const float4* __restrict__ s4,   // packed j-tile: 3 float4 per 2 j-points
    float pix, float piy, float piz,
    float tix, float tiy, float tiz,
    unsigned& c0, unsigned& c1, unsigned& c2, unsigned& c3, unsigned& cd)
{
    #pragma unroll 4
    for (int q = 0; q < TJ / 2; ++q) {
        // same address across all 64 lanes -> LDS broadcast, conflict-free
        float4 A  = s4[3 * q + 0];  // {p0.x, p0.y, p0.z, t0.x}
        float4 Bq = s4[3 * q + 1];  // {t0.y, t0.z, p1.x, p1.y}
        float4 Cq = s4[3 * q + 2];  // {p1.z, t1.x, t1.y, t1.z}

        do_pair<CHECK>(A.x, A.y, A.z, A.w, Bq.x, Bq.y,
                       pix, piy, piz, tix, tiy, tiz, 2 * q,
                       c0, c1, c2, c3, cd);
        do_pair<CHECK>(Bq.z, Bq.w, Cq.x, Cq.y, Cq.z, Cq.w,
                       pix, piy, piz, tix, tiy, tiz, 2 * q + 1,
                       c0, c1, c2, c3, cd);
    }
}

__global__ __launch_bounds__(TI) void lddt_partial(
    const float* __restrict__ pred,   // [B,N,3]
    const float* __restrict__ truec,  // [B,N,3]
    float* __restrict__ part)         // [B,TILES,2]
{
    const int b = blockIdx.y;
    // decode linear tile index -> (a = i-tile, k = j-subtile rel. index)
    int r = blockIdx.x, a = 0;
    while (r >= 32 - 8 * a) { r -= 32 - 8 * a; ++a; }
    const int k = r;                  // c = 8a + k, k in [0, 32-8a)
    const int i0 = a * TI;
    const int j0 = (8 * a + k) * TJ;
    const int t = threadIdx.x;
    const int w = t >> 6;             // wave 0..7; wave w owns i in
    const int lane = t & 63;          //   [i0+64w, i0+64w+64) = tile (8a+w)

    // packed j-tile: sj[6*j .. 6*j+5] = {px,py,pz,tx,ty,tz} of point j0+j
    __shared__ float sj[TJ * 6];
    if (t < TJ) {
        const float* pp = pred  + ((size_t)b * N + j0 + t) * 3;
        const float* tp = truec + ((size_t)b * N + j0 + t) * 3;
        sj[6 * t + 0] = pp[0];
        sj[6 * t + 1] = pp[1];
        sj[6 * t + 2] = pp[2];
        sj[6 * t + 3] = tp[0];
        sj[6 * t + 4] = tp[1];
        sj[6 * t + 5] = tp[2];
    }
    __syncthreads();

    unsigned c0 = 0, c1 = 0, c2 = 0, c3 = 0, cd = 0;

    if (k >= w) {                     // k<w: whole wave is j<i -> zero
        const int i = i0 + t;
        const float* pi = pred  + ((size_t)b * N + i) * 3;
        const float* ti = truec + ((size_t)b * N + i) * 3;
        const float pix = pi[0], piy = pi[1], piz = pi[2];
        const float tix = ti[0], tiy = ti[1], tiz = ti[2];
        const float4* s4 = reinterpret_cast<const float4*>(sj);

        if (k > w) {                  // strictly above diagonal: no check
            inner_loop<false>(s4, pix, piy, piz, tix, tiy, tiz,
                              c0, c1, c2, c3, cd);
        } else {                      // k == w: diagonal 64x64 block
            inner_loop<true>(s4, pix, piy, piz, tix, tiy, tiz,
                             c0, c1, c2, c3, cd);
        }
    }

    // counters are wave-uniform (ballot-derived): lane 0 of each wave has them
    __shared__ float rnum[TI / 64];
    __shared__ float rden[TI / 64];
    if (lane == 0) {
        rnum[w] = 0.125f * (float)(4u * c0 + 2u * c1 + c2 + c3);
        rden[w] = (float)cd;
    }
    __syncthreads();

    if (t == 0) {
        float n = 0.0f, d = 0.0f;
        #pragma unroll
        for (int q = 0; q < TI / 64; ++q) { n += rnum[q]; d += rden[q]; }
        // plain store to this block's private slot -- NO atomics, no memset
        float* slot = part + ((size_t)b * TILES + blockIdx.x) * 2;
        slot[0] = n;
        slot[1] = d;
    }
}

// 512 threads = 8 waves; wave w reduces batch w's 80 slots.
__global__ __launch_bounds__(512) void lddt_reduce(
    const float* __restrict__ part,   // [B,TILES,2]
    float* __restrict__ out)          // [1]
{
    const int t = threadIdx.x;
    const int w = t >> 6;     // batch
    const int l = t & 63;

    float n = 0.0f, d = 0.0f;
    for (int s = l; s < TILES; s += 64) {
        const float* slot = part + ((size_t)w * TILES + s) * 2;
        n += slot[0];
        d += slot[1];
    }
    #pragma unroll
    for (int off = 32; off > 0; off >>= 1) {
        n += __shfl_down(n, off, 64);
        d += __shfl_down(d, off, 64);
    }

    __shared__ float acc[B];
    if (l == 0) acc[w] = 1.0f - n / fmaxf(d, 1e-8f);
    __syncthreads();

    if (t == 0) {
        float s = 0.0f;
        #pragma unroll
        for (int b = 0; b < B; ++b) s += acc[b];
        out[0] = s / (float)B;
    }
}

extern "C" void kernel_launch(void* const* d_in, const int* in_sizes, int n_in,
                              void* d_out, int out_size, void* d_ws, size_t ws_size,
                              hipStream_t stream)
{
    const float* pred  = (const float*)d_in[0];
    const float* truec = (const float*)d_in[1];
    float* out  = (float*)d_out;
    float* part = (float*)d_ws;   // B*TILES*2 floats = 5120 B

    dim3 grid(TILES, B);
    lddt_partial<<<grid, TI, 0, stream>>>(pred, truec, part);
    lddt_reduce<<<1, 512, 0, stream>>>(part, out);
}

// Round 7
// 70.729 us; speedup vs baseline: 2.1381x; 1.0407x over previous
//
#include <hip/hip_runtime.h>
#include <math.h>

// B=8, N=2048, coords [B,N,3] f32. LDDT loss, upper-triangle formulation:
// both distance matrices are symmetric, so num/den over {j>i} equals the
// full-matrix ratio; j>i also excludes the diagonal (reference's
// true_d > 1e-8 test is vacuous for distinct points).
//
// V8: discriminating experiment for the latency/critical-path theory.
// Same proven inner step as V4 (packed j-tile LDS broadcast, ballot+
// popcount, constant diagonal masks), but TJ 64->32: each wave's serial
// j-loop halves (64->32 dependent steps), wave count doubles (2304 blocks
// x 4 waves ~ 36/CU). Total pair-work identical. If wall time is set by
// the per-wave dependency chain (consistent with V4 neutral at -25%
// instructions, V7 worse at -44% blocks, pipes <50% busy), partial wall
// should drop ~2x. If neutral: issue/fixed-overhead floor -> stop.
// Dead ends (measured): V2 uniform-pointer loads, V3 v_readlane, V5
// cooperative grid.sync (+60us), V6 last-block atomic+fence (+80us),
// V7 TI=512 (+2.3us).
// Exactness: per-slot num is a multiple of 1/8, 8*num < 2^24, den < 2^24
// -> fp32 sums exact in ANY order -> reduce order change is bit-safe.
constexpr int B  = 8;
constexpr int N  = 2048;
constexpr int TI = 256;        // i-points per block (4 waves)
constexpr int TJ = 32;         // j-points per block (half a wave-width)
constexpr int TILES = 288;     // sum_{a=0..7} (64 - 8a): j-tiles with any j>i

// one i-vs-j pair step; CHECK: diagonal half-tile, mask lanes < jbase+jj
template <bool CHECK>
__device__ __forceinline__ void do_pair(
    float jx, float jy, float jz, float ux, float uy, float uz,
    float pix, float piy, float piz, float tix, float tiy, float tiz,
    int jj, int jbase,
    unsigned& c0, unsigned& c1, unsigned& c2, unsigned& c3, unsigned& cd)
{
    float dx = pix - jx, dy = piy - jy, dz = piz - jz;
    float pd2 = fmaf(dx, dx, fmaf(dy, dy, dz * dz));
    float ex = tix - ux, ey = tiy - uy, ez = tiz - uz;
    float td2 = fmaf(ex, ex, fmaf(ey, ey, ez * ez));

    // local mask (squared domain): true_d < 15
    unsigned long long m = __ballot(td2 < 225.0f);
    // diagonal: j>i <=> lane < jbase+jj (jbase+jj <= 63 here) -> const mask
    if (CHECK) m &= (1ull << (jbase + jj)) - 1ull;

    float diff = fabsf(__builtin_amdgcn_sqrtf(pd2) - __builtin_amdgcn_sqrtf(td2));

    // cumulative bins: score = .5*[d<.5] + .25*[d<1] + .125*[d<2] + .125*[d<4]
    c0 += __popcll(m & __ballot(diff < 0.5f));
    c1 += __popcll(m & __ballot(diff < 1.0f));
    c2 += __popcll(m & __ballot(diff < 2.0f));
    c3 += __popcll(m & __ballot(diff < 4.0f));
    cd += __popcll(m);
}

template <bool CHECK>
__device__ __forceinline__ void inner_loop(
    const float4* __restrict__ s4,   // packed j-tile: 3 float4 per 2 j-points
    float pix, float piy, float piz,
    float tix, float tiy, float tiz,
    int jbase,
    unsigned& c0, unsigned& c1, unsigned& c2, unsigned& c3, unsigned& cd)
{
    #pragma unroll 4
    for (int q = 0; q < TJ / 2; ++q) {
        // same address across all 64 lanes -> LDS broadcast, conflict-free
        float4 A  = s4[3 * q + 0];  // {p0.x, p0.y, p0.z, t0.x}
        float4 Bq = s4[3 * q + 1];  // {t0.y, t0.z, p1.x, p1.y}
        float4 Cq = s4[3 * q + 2];  // {p1.z, t1.x, t1.y, t1.z}

        do_pair<CHECK>(A.x, A.y, A.z, A.w, Bq.x, Bq.y,
                       pix, piy, piz, tix, tiy, tiz, 2 * q, jbase,
                       c0, c1, c2, c3, cd);
        do_pair<CHECK>(Bq.z, Bq.w, Cq.x, Cq.y, Cq.z, Cq.w,
                       pix, piy, piz, tix, tiy, tiz, 2 * q + 1, jbase,
                       c0, c1, c2, c3, cd);
    }
}

__global__ __launch_bounds__(TI) void lddt_partial(
    const float* __restrict__ pred,   // [B,N,3]
    const float* __restrict__ truec,  // [B,N,3]
    float* __restrict__ part)         // [B,TILES,2]
{
    const int b = blockIdx.y;
    // decode linear tile index -> (a = i-tile of 256, k = j-subtile rel idx)
    int r = blockIdx.x, a = 0;
    while (r >= 64 - 8 * a) { r -= 64 - 8 * a; ++a; }
    const int k = r;                  // c = 8a + k, k in [0, 64-8a)
    const int i0 = a * TI;
    const int j0 = (8 * a + k) * TJ;
    const int t = threadIdx.x;
    const int w = t >> 6;             // wave 0..3 owns i in [i0+64w, i0+64w+64)
    const int lane = t & 63;

    // packed j-tile: sj[6*j .. 6*j+5] = {px,py,pz,tx,ty,tz} of point j0+j
    __shared__ float sj[TJ * 6];
    if (t < TJ) {
        const float* pp = pred  + ((size_t)b * N + j0 + t) * 3;
        const float* tp = truec + ((size_t)b * N + j0 + t) * 3;
        sj[6 * t + 0] = pp[0];
        sj[6 * t + 1] = pp[1];
        sj[6 * t + 2] = pp[2];
        sj[6 * t + 3] = tp[0];
        sj[6 * t + 4] = tp[1];
        sj[6 * t + 5] = tp[2];
    }
    __syncthreads();

    unsigned c0 = 0, c1 = 0, c2 = 0, c3 = 0, cd = 0;

    // wave's i-subtile (64-wide) index rel. to block: w; j-subtile: k.
    // k >= 2w+2: fully above diagonal (no check); k == 2w: diagonal lower
    // half (jbase=0); k == 2w+1: diagonal upper half (jbase=32);
    // k < 2w: fully below -> wave contributes zero.
    if (k >= 2 * w) {
        const int i = i0 + t;
        const float* pi = pred  + ((size_t)b * N + i) * 3;
        const float* ti = truec + ((size_t)b * N + i) * 3;
        const float pix = pi[0], piy = pi[1], piz = pi[2];
        const float tix = ti[0], tiy = ti[1], tiz = ti[2];
        const float4* s4 = reinterpret_cast<const float4*>(sj);

        if (k >= 2 * w + 2) {
            inner_loop<false>(s4, pix, piy, piz, tix, tiy, tiz, 0,
                              c0, c1, c2, c3, cd);
        } else {
            const int jbase = (k == 2 * w) ? 0 : 32;
            inner_loop<true>(s4, pix, piy, piz, tix, tiy, tiz, jbase,
                             c0, c1, c2, c3, cd);
        }
    }

    // counters are wave-uniform (ballot-derived): lane 0 of each wave has them
    __shared__ float rnum[TI / 64];
    __shared__ float rden[TI / 64];
    if (lane == 0) {
        rnum[w] = 0.125f * (float)(4u * c0 + 2u * c1 + c2 + c3);
        rden[w] = (float)cd;
    }
    __syncthreads();

    if (t == 0) {
        float n = 0.0f, d = 0.0f;
        #pragma unroll
        for (int q = 0; q < TI / 64; ++q) { n += rnum[q]; d += rden[q]; }
        // plain store to this block's private slot -- NO atomics, no memset
        float* slot = part + ((size_t)b * TILES + blockIdx.x) * 2;
        slot[0] = n;
        slot[1] = d;
    }
}

// 512 threads = 8 waves; wave w reduces batch w's 288 slots.
__global__ __launch_bounds__(512) void lddt_reduce(
    const float* __restrict__ part,   // [B,TILES,2]
    float* __restrict__ out)          // [1]
{
    const int t = threadIdx.x;
    const int w = t >> 6;     // batch
    const int l = t & 63;

    float n = 0.0f, d = 0.0f;
    for (int s = l; s < TILES; s += 64) {
        const float* slot = part + ((size_t)w * TILES + s) * 2;
        n += slot[0];
        d += slot[1];
    }
    #pragma unroll
    for (int off = 32; off > 0; off >>= 1) {
        n += __shfl_down(n, off, 64);
        d += __shfl_down(d, off, 64);
    }

    __shared__ float acc[B];
    if (l == 0) acc[w] = 1.0f - n / fmaxf(d, 1e-8f);
    __syncthreads();

    if (t == 0) {
        float s = 0.0f;
        #pragma unroll
        for (int b = 0; b < B; ++b) s += acc[b];
        out[0] = s / (float)B;
    }
}

extern "C" void kernel_launch(void* const* d_in, const int* in_sizes, int n_in,
                              void* d_out, int out_size, void* d_ws, size_t ws_size,
                              hipStream_t stream)
{
    const float* pred  = (const float*)d_in[0];
    const float* truec = (const float*)d_in[1];
    float* out  = (float*)d_out;
    float* part = (float*)d_ws;   // B*TILES*2 floats = 18432 B

    dim3 grid(TILES, B);
    lddt_partial<<<grid, TI, 0, stream>>>(pred, truec, part);
    lddt_reduce<<<1, 512, 0, stream>>>(part, out);
}